// Round 11
// baseline (174.574 us; speedup 1.0000x reference)
//
#include <hip/hip_runtime.h>
#include <cmath>

// Static problem config (matches reference)
#define RB 20
#define RA 19
#define NPT (RB*RA)
#define DZ 25
#define DIN 9
#define MULT 128
#define CH 128

// ---------------------------------------------------------------------------
// Host: transposed dense real-Gaunt table Gt[d1*9+d2][28] in fp64 from the
// reference's own quadrature (exact bilinear identity). Row entries 25..27
// stay zero (padding used by the kernel's uniform 13-FMA body).
static void host_build_gaunt(float* out /* 81*28, zero-padded */) {
    const double PI = 3.14159265358979323846;
    double xq[RB], wq[RB];
    for (int i = 0; i < RB; ++i) {
        double x = cos(PI * (i + 0.75) / (RB + 0.5));
        double dp = 0.0;
        for (int it = 0; it < 100; ++it) {
            double p0 = 1.0, p1 = x;
            for (int k = 2; k <= RB; ++k) {
                double p2 = ((2.0*k - 1.0)*x*p1 - (k - 1.0)*p0) / (double)k;
                p0 = p1; p1 = p2;
            }
            dp = RB * (x*p1 - p0) / (x*x - 1.0);
            double dx = p1 / dp;
            x -= dx;
            if (fabs(dx) < 1e-15) break;
        }
        {
            double p0 = 1.0, p1 = x;
            for (int k = 2; k <= RB; ++k) {
                double p2 = ((2.0*k - 1.0)*x*p1 - (k - 1.0)*p0) / (double)k;
                p0 = p1; p1 = p2;
            }
            dp = RB * (x*p1 - p0) / (x*x - 1.0);
        }
        xq[i] = x;
        wq[i] = 2.0 / ((1.0 - x*x)*dp*dp);
    }
    static double Y[DZ][NPT];
    static double qws[NPT];
    for (int b = 0; b < RB; ++b) {
        double ct = xq[b], st = sqrt(fmax(0.0, 1.0 - ct*ct));
        double P[5][5]; double pmm = 1.0;
        for (int m = 0; m <= 4; ++m) {
            if (m > 0) pmm *= -(2.0*m - 1.0) * st;
            P[m][m] = pmm;
            if (m < 4) {
                double pp = pmm, pc = ct*(2.0*m + 1.0)*pmm;
                P[m+1][m] = pc;
                for (int l = m + 2; l <= 4; ++l) {
                    double pn = ((2.0*l - 1.0)*ct*pc - (double)(l + m - 1)*pp) / (double)(l - m);
                    P[l][m] = pn; pp = pc; pc = pn;
                }
            }
        }
        for (int a = 0; a < RA; ++a) {
            int pt = b*RA + a;
            qws[pt] = wq[b] * (2.0*PI/(double)RA);
            double alpha = 2.0*PI*(double)a/(double)RA;
            for (int l = 0; l <= 4; ++l)
                for (int m = -l; m <= l; ++m) {
                    int am = m < 0 ? -m : m;
                    double fr = 1.0;
                    for (int i = l - am + 1; i <= l + am; ++i) fr *= (double)i;
                    double nlm = sqrt((2.0*l + 1.0) / (4.0*PI) / fr);
                    double ang = (m == 0) ? 1.0
                               : (m > 0 ? sqrt(2.0)*cos(am*alpha) : sqrt(2.0)*sin(am*alpha));
                    Y[l*l + l + m][pt] = nlm * P[l][am] * ang;
                }
        }
    }
    for (int pr = 0; pr < 81; ++pr) {
        int d1 = pr / 9, d2 = pr % 9;
        for (int d = 0; d < DZ; ++d) {
            double s = 0.0;
            for (int p = 0; p < NPT; ++p)
                s += Y[d][p] * Y[d1][p] * Y[d2][p] * qws[p];
            out[pr*28 + d] = (float)s;
        }
        // pads [25..27] remain zero (static storage)
    }
}

// ---------------------------------------------------------------------------
// Kernel 1: linear_in + Gaunt contraction. Writes z to d_out as [n][dz][c].
// Wave-balanced: stage B wave = (side, c-half), lane owns one c, 9 d-accs;
// x and G are read via wave-uniform indices from const __restrict__ pointers
// (scalar-load eligible). LDS only for xc/yc (18.4 KB).
__global__ __launch_bounds__(256) void k1_in_gaunt(
    const float* __restrict__ xg, const float* __restrict__ yg,
    const float* __restrict__ wxg, const float* __restrict__ wyg,
    const float* __restrict__ gGt, float* __restrict__ zg) {

    __shared__ float sXc[DIN * CH];   // xc [d][c]
    __shared__ float sYc[DIN * CH];
    const int tid = threadIdx.x;
    const int n = blockIdx.x;
    const int lane = tid & 63;
    const int wave = __builtin_amdgcn_readfirstlane(tid >> 6);
    const float s128 = 0.08838834764831845f;   // 1/sqrt(128)

    // Stage B: xc[d][c] = (1/sqrt(128)) sum_m x[m][d] * w_{l(d)}[m][c]
    {
        const int side = wave >> 1;                 // 0=x, 1=y (wave-uniform)
        const int c = ((wave & 1) << 6) + lane;     // c in [0,128)
        const float* xp = (side ? yg : xg) + n * (MULT * DIN);
        const float* wb = side ? wyg : wxg;
        float acc[9];
        #pragma unroll
        for (int d = 0; d < 9; ++d) acc[d] = 0.f;
        for (int m = 0; m < MULT; m += 4) {
            float w0[4], w1[4], w2[4];
            #pragma unroll
            for (int k = 0; k < 4; ++k) {
                w0[k] = wb[(m + k) * 128 + c];            // l=0
                w1[k] = wb[16384 + (m + k) * 128 + c];    // l=1
                w2[k] = wb[32768 + (m + k) * 128 + c];    // l=2
            }
            #pragma unroll
            for (int k = 0; k < 4; ++k) {
                const float* xr = xp + (m + k) * 9;       // uniform -> s_load
                acc[0] = fmaf(xr[0], w0[k], acc[0]);
                acc[1] = fmaf(xr[1], w1[k], acc[1]);
                acc[2] = fmaf(xr[2], w1[k], acc[2]);
                acc[3] = fmaf(xr[3], w1[k], acc[3]);
                acc[4] = fmaf(xr[4], w2[k], acc[4]);
                acc[5] = fmaf(xr[5], w2[k], acc[5]);
                acc[6] = fmaf(xr[6], w2[k], acc[6]);
                acc[7] = fmaf(xr[7], w2[k], acc[7]);
                acc[8] = fmaf(xr[8], w2[k], acc[8]);
            }
        }
        float* dst = side ? sYc : sXc;
        #pragma unroll
        for (int d = 0; d < 9; ++d) dst[d * 128 + c] = acc[d] * s128;
    }
    __syncthreads();

    // Stage C: z[dz][c] = sum_{d1,d2} Gt[d1*9+d2][dz] * xc[d1][c] * yc[d2][c]
    {
        const int c = tid & 127;
        const int half = __builtin_amdgcn_readfirstlane(tid >> 7);
        const int dz0 = half ? 13 : 0;      // half0: dz 0-12, half1: dz 13-24 (+pad)
        float xr[9], yr[9];
        #pragma unroll
        for (int d = 0; d < 9; ++d) { xr[d] = sXc[d*128 + c]; yr[d] = sYc[d*128 + c]; }
        float acc[13];
        #pragma unroll
        for (int i = 0; i < 13; ++i) acc[i] = 0.f;
        for (int d1 = 0; d1 < 9; ++d1) {
            #pragma unroll
            for (int d2 = 0; d2 < 9; ++d2) {
                float p = xr[d1] * yr[d2];
                const float* gt = gGt + (d1 * 9 + d2) * 28 + dz0;  // uniform -> s_load
                #pragma unroll
                for (int i = 0; i < 13; ++i) acc[i] = fmaf(p, gt[i], acc[i]);
            }
        }
        float* zp = zg + n * (CH * DZ);
        if (half == 0) {
            #pragma unroll
            for (int i = 0; i < 13; ++i) zp[i * 128 + c] = acc[i];
        } else {
            #pragma unroll
            for (int i = 0; i < 12; ++i) zp[(13 + i) * 128 + c] = acc[i];  // acc[12] = pad, dropped
        }
    }
}

// ---------------------------------------------------------------------------
// Kernel 2: linear_out, in place over d_out (z [n][dz][c] -> out [n][e][25]).
// Wave = l-aligned dz-range (wz read exactly once per block); lane owns e and
// e+64. z read via uniform-address float4 broadcast loads. All z reads happen
// before the barrier; all global out stores after it -> in-place safe.
template<int D0, int ND>
__device__ __forceinline__ void k2_tile(const float* __restrict__ zp,
                                        const float* __restrict__ wzg,
                                        float* sOut, int lane) {
    const float s128 = 0.08838834764831845f;
    float acc[2 * ND];
    #pragma unroll
    for (int i = 0; i < 2 * ND; ++i) acc[i] = 0.f;
    for (int c0 = 0; c0 < CH; c0 += 4) {
        float4 zv[ND];
        #pragma unroll
        for (int i = 0; i < ND; ++i)
            zv[i] = *(const float4*)(zp + (D0 + i) * 128 + c0);   // uniform, aligned
        #pragma unroll
        for (int k = 0; k < 4; ++k) {
            #pragma unroll
            for (int i = 0; i < ND; ++i) {
                const int d = D0 + i;
                const int l = (d == 0) ? 0 : (d < 4) ? 1 : (d < 9) ? 2 : (d < 16) ? 3 : 4;
                float wA = wzg[l * 16384 + (c0 + k) * 128 + lane];        // CSE'd per l
                float wB = wzg[l * 16384 + (c0 + k) * 128 + lane + 64];
                float zc = (k == 0) ? zv[i].x : (k == 1) ? zv[i].y
                         : (k == 2) ? zv[i].z : zv[i].w;
                acc[2 * i]     = fmaf(zc, wA, acc[2 * i]);
                acc[2 * i + 1] = fmaf(zc, wB, acc[2 * i + 1]);
            }
        }
    }
    #pragma unroll
    for (int i = 0; i < ND; ++i) {
        sOut[lane * 25 + D0 + i]        = acc[2 * i] * s128;
        sOut[(lane + 64) * 25 + D0 + i] = acc[2 * i + 1] * s128;
    }
}

__global__ __launch_bounds__(256) void k2_out(const float* __restrict__ wzg,
                                              float* outg) {
    __shared__ __align__(16) float sOut[CH * DZ];
    const int tid = threadIdx.x;
    const int n = blockIdx.x;
    const int lane = tid & 63;
    const int wave = __builtin_amdgcn_readfirstlane(tid >> 6);
    const float* zp = outg + n * (CH * DZ);    // z written by k1 (same buffer)

    if      (wave == 0) k2_tile<0, 4>(zp, wzg, sOut, lane);   // l0+l1: d0-3
    else if (wave == 1) k2_tile<4, 5>(zp, wzg, sOut, lane);   // l2: d4-8
    else if (wave == 2) k2_tile<9, 7>(zp, wzg, sOut, lane);   // l3: d9-15
    else                k2_tile<16, 9>(zp, wzg, sOut, lane);  // l4: d16-24
    __syncthreads();   // ALL z reads complete before ANY out store below

    float* po = outg + n * (CH * DZ);
    const float4* so = (const float4*)sOut;
    for (int j = tid; j < (CH * DZ) / 4; j += 256)
        ((float4*)po)[j] = so[j];
}

extern "C" void kernel_launch(void* const* d_in, const int* in_sizes, int n_in,
                              void* d_out, int out_size, void* d_ws, size_t ws_size,
                              hipStream_t stream) {
    // Gaunt table on host (fp64), 9 KB H2D per call (graph-capture safe).
    static float h_gGt[81 * 28];   // zero-init pads [25..27] per row
    host_build_gaunt(h_gGt);
    hipMemcpyAsync(d_ws, h_gGt, sizeof(h_gGt), hipMemcpyHostToDevice, stream);

    int N = in_sizes[0] / (MULT * DIN);

    hipLaunchKernelGGL(k1_in_gaunt, dim3(N), dim3(256), 0, stream,
                       (const float*)d_in[0], (const float*)d_in[1],
                       (const float*)d_in[2], (const float*)d_in[3],
                       (const float*)d_ws, (float*)d_out);
    hipLaunchKernelGGL(k2_out, dim3(N), dim3(256), 0, stream,
                       (const float*)d_in[4], (float*)d_out);
}

// Round 12
// 118.744 us; speedup vs baseline: 1.4702x; 1.4702x over previous
//
#include <hip/hip_runtime.h>
#include <cmath>

// Static problem config (matches reference)
#define RB 20
#define RA 19
#define NPT (RB*RA)
#define DZ 25
#define DIN 9
#define MULT 128
#define CH 128

// ---------------------------------------------------------------------------
// Host: transposed dense real-Gaunt table Gt[d1*9+d2][28] in fp64 from the
// reference's own quadrature (exact bilinear identity). Cols 25..27 zero pads.
static void host_build_gaunt(float* out /* 81*28, zero-padded */) {
    const double PI = 3.14159265358979323846;
    double xq[RB], wq[RB];
    for (int i = 0; i < RB; ++i) {
        double x = cos(PI * (i + 0.75) / (RB + 0.5));
        double dp = 0.0;
        for (int it = 0; it < 100; ++it) {
            double p0 = 1.0, p1 = x;
            for (int k = 2; k <= RB; ++k) {
                double p2 = ((2.0*k - 1.0)*x*p1 - (k - 1.0)*p0) / (double)k;
                p0 = p1; p1 = p2;
            }
            dp = RB * (x*p1 - p0) / (x*x - 1.0);
            double dx = p1 / dp;
            x -= dx;
            if (fabs(dx) < 1e-15) break;
        }
        {
            double p0 = 1.0, p1 = x;
            for (int k = 2; k <= RB; ++k) {
                double p2 = ((2.0*k - 1.0)*x*p1 - (k - 1.0)*p0) / (double)k;
                p0 = p1; p1 = p2;
            }
            dp = RB * (x*p1 - p0) / (x*x - 1.0);
        }
        xq[i] = x;
        wq[i] = 2.0 / ((1.0 - x*x)*dp*dp);
    }
    static double Y[DZ][NPT];
    static double qws[NPT];
    for (int b = 0; b < RB; ++b) {
        double ct = xq[b], st = sqrt(fmax(0.0, 1.0 - ct*ct));
        double P[5][5]; double pmm = 1.0;
        for (int m = 0; m <= 4; ++m) {
            if (m > 0) pmm *= -(2.0*m - 1.0) * st;
            P[m][m] = pmm;
            if (m < 4) {
                double pp = pmm, pc = ct*(2.0*m + 1.0)*pmm;
                P[m+1][m] = pc;
                for (int l = m + 2; l <= 4; ++l) {
                    double pn = ((2.0*l - 1.0)*ct*pc - (double)(l + m - 1)*pp) / (double)(l - m);
                    P[l][m] = pn; pp = pc; pc = pn;
                }
            }
        }
        for (int a = 0; a < RA; ++a) {
            int pt = b*RA + a;
            qws[pt] = wq[b] * (2.0*PI/(double)RA);
            double alpha = 2.0*PI*(double)a/(double)RA;
            for (int l = 0; l <= 4; ++l)
                for (int m = -l; m <= l; ++m) {
                    int am = m < 0 ? -m : m;
                    double fr = 1.0;
                    for (int i = l - am + 1; i <= l + am; ++i) fr *= (double)i;
                    double nlm = sqrt((2.0*l + 1.0) / (4.0*PI) / fr);
                    double ang = (m == 0) ? 1.0
                               : (m > 0 ? sqrt(2.0)*cos(am*alpha) : sqrt(2.0)*sin(am*alpha));
                    Y[l*l + l + m][pt] = nlm * P[l][am] * ang;
                }
        }
    }
    for (int pr = 0; pr < 81; ++pr) {
        int d1 = pr / 9, d2 = pr % 9;
        for (int d = 0; d < DZ; ++d) {
            double s = 0.0;
            for (int p = 0; p < NPT; ++p)
                s += Y[d][p] * Y[d1][p] * Y[d2][p] * qws[p];
            out[pr*28 + d] = (float)s;
        }
    }
}

// ---------------------------------------------------------------------------
// Stage D helper: wave handles d-range [D0, D0+ND) (l-aligned, so wz_l is
// read exactly once per block); lane owns e=lane and e+64; both nodes inner.
// z read as same-address LDS b32 broadcasts (conflict-free).
template<int D0, int ND>
__device__ __forceinline__ void d_tile(const float* sZ, const float* __restrict__ wz,
                                       float* sOut, int lane) {
    const float s128 = 0.08838834764831845f;
    float acc[ND * 4];   // [i][n*2+eh]
    #pragma unroll
    for (int i = 0; i < ND * 4; ++i) acc[i] = 0.f;
    for (int c = 0; c < CH; ++c) {
        #pragma unroll
        for (int i = 0; i < ND; ++i) {
            const int d = D0 + i;
            const int l = (d == 0) ? 0 : (d < 4) ? 1 : (d < 9) ? 2 : (d < 16) ? 3 : 4;
            float wa = wz[l * 16384 + c * 128 + lane];        // CSE'd across same-l i's
            float wb = wz[l * 16384 + c * 128 + lane + 64];
            float z0 = sZ[(d) * 128 + c];                     // node 0, broadcast
            float z1 = sZ[(25 + d) * 128 + c];                // node 1, broadcast
            acc[i*4+0] = fmaf(z0, wa, acc[i*4+0]);
            acc[i*4+1] = fmaf(z0, wb, acc[i*4+1]);
            acc[i*4+2] = fmaf(z1, wa, acc[i*4+2]);
            acc[i*4+3] = fmaf(z1, wb, acc[i*4+3]);
        }
    }
    #pragma unroll
    for (int i = 0; i < ND; ++i) {
        sOut[(lane) * 25 + D0 + i]            = acc[i*4+0] * s128;
        sOut[(lane + 64) * 25 + D0 + i]       = acc[i*4+1] * s128;
        sOut[(128 + lane) * 25 + D0 + i]      = acc[i*4+2] * s128;
        sOut[(128 + lane + 64) * 25 + D0 + i] = acc[i*4+3] * s128;
    }
}

// ---------------------------------------------------------------------------
// Fully fused, 2 nodes per block, z in LDS (no global roundtrip).
__global__ __launch_bounds__(256) void gaunt_fused(
    const float* __restrict__ xg, const float* __restrict__ yg,
    const float* __restrict__ wxg, const float* __restrict__ wyg,
    const float* __restrict__ wzg, float* __restrict__ outg,
    const float* __restrict__ gGt) {

    // LDS pool (floats), 15616 = 62464 B (< 64 KB workgroup limit):
    //  sZ   [0,     6400)  z [n][dz][c]
    //  sXY  [6400, 11008)  x,y transposed [side][n][d*128+m]  (stages A/B)
    //  sG   [6400,  8668)  Gaunt table (stage C; aliases dead sXY)
    //  sOut [6400, 12800)  out [n][e][25]  (stage D/E; aliases sXY/sG/sXc)
    //  sXc  [11008,15616)  xc [side][d][n][c]  (stages B/C)
    __shared__ __align__(16) float pool[15616];
    float* sZ   = pool;
    float* sXY  = pool + 6400;
    float* sG   = pool + 6400;
    float* sOut = pool + 6400;
    float* sXc  = pool + 11008;

    const int tid  = threadIdx.x;
    const int b    = blockIdx.x;
    const int lane = tid & 63;
    const int wave = __builtin_amdgcn_readfirstlane(tid >> 6);
    const float s128 = 0.08838834764831845f;   // 1/sqrt(128)

    // Stage A: load x,y for nodes 2b,2b+1; transpose to [side][n][d*128+m]
    {
        const float4* xs = (const float4*)(xg + 2 * b * 1152);
        const float4* ys = (const float4*)(yg + 2 * b * 1152);
        for (int i = tid; i < 1152; i += 256) {
            float4 v = (i < 576) ? xs[i] : ys[i - 576];
            int r = (i < 576) ? i : i - 576;
            int base = (i < 576) ? 0 : 2304;
            int j0 = r * 4;
            #pragma unroll
            for (int k = 0; k < 4; ++k) {
                int j = j0 + k;
                int n = j / 1152;
                int jj = j - n * 1152;
                int m = jj / 9, d = jj - 9 * m;
                float val = (k == 0) ? v.x : (k == 1) ? v.y : (k == 2) ? v.z : v.w;
                sXY[base + n * 1152 + d * 128 + m] = val;
            }
        }
    }
    __syncthreads();

    // Stage B: linear_in. wave=(side,chalf), lane owns one c; both nodes.
    // x fragments are aligned ds_read_b128 broadcasts; weights coalesced.
    {
        const int side = wave >> 1, ch = wave & 1;
        const int c = ch * 64 + lane;
        const float* wb = side ? wyg : wxg;
        const float* xb = sXY + side * 2304;   // [n][d*128+m]
        float acc[18];                          // [d][n]
        #pragma unroll
        for (int i = 0; i < 18; ++i) acc[i] = 0.f;
        for (int m0 = 0; m0 < MULT; m0 += 4) {
            float w0[4], w1[4], w2[4];
            #pragma unroll
            for (int k = 0; k < 4; ++k) {
                w0[k] = wb[(m0 + k) * 128 + c];
                w1[k] = wb[16384 + (m0 + k) * 128 + c];
                w2[k] = wb[32768 + (m0 + k) * 128 + c];
            }
            #pragma unroll
            for (int d = 0; d < 9; ++d) {
                const float* wl = (d == 0) ? w0 : (d < 4) ? w1 : w2;
                float4 x0 = *(const float4*)(xb + d * 128 + m0);
                float4 x1 = *(const float4*)(xb + 1152 + d * 128 + m0);
                acc[d*2+0] = fmaf(x0.x, wl[0], acc[d*2+0]);
                acc[d*2+0] = fmaf(x0.y, wl[1], acc[d*2+0]);
                acc[d*2+0] = fmaf(x0.z, wl[2], acc[d*2+0]);
                acc[d*2+0] = fmaf(x0.w, wl[3], acc[d*2+0]);
                acc[d*2+1] = fmaf(x1.x, wl[0], acc[d*2+1]);
                acc[d*2+1] = fmaf(x1.y, wl[1], acc[d*2+1]);
                acc[d*2+1] = fmaf(x1.z, wl[2], acc[d*2+1]);
                acc[d*2+1] = fmaf(x1.w, wl[3], acc[d*2+1]);
            }
        }
        #pragma unroll
        for (int d = 0; d < 9; ++d) {
            sXc[((side * 9 + d) * 2 + 0) * 128 + c] = acc[d*2+0] * s128;
            sXc[((side * 9 + d) * 2 + 1) * 128 + c] = acc[d*2+1] * s128;
        }
    }
    __syncthreads();

    // Stage B2: Gaunt table -> LDS (over dead sXY region)
    for (int i = tid; i < 81 * 28; i += 256) sG[i] = gGt[i];
    __syncthreads();

    // Stage C: z[n][dz][c] = sum_{d1,d2} G[dz][d1,d2] xc[d1][c] yc[d2][c]
    {
        const int c = tid & 127;
        const int half = __builtin_amdgcn_readfirstlane(tid >> 7);
        const int dz0 = half ? 13 : 0;
        float xr0[9], xr1[9], yr0[9], yr1[9];
        #pragma unroll
        for (int d = 0; d < 9; ++d) {
            xr0[d] = sXc[(d * 2 + 0) * 128 + c];
            xr1[d] = sXc[(d * 2 + 1) * 128 + c];
            yr0[d] = sXc[((9 + d) * 2 + 0) * 128 + c];
            yr1[d] = sXc[((9 + d) * 2 + 1) * 128 + c];
        }
        float a0[13], a1[13];
        #pragma unroll
        for (int i = 0; i < 13; ++i) { a0[i] = 0.f; a1[i] = 0.f; }
        for (int d1 = 0; d1 < 9; ++d1) {
            #pragma unroll
            for (int d2 = 0; d2 < 9; ++d2) {
                float p0 = xr0[d1] * yr0[d2];
                float p1 = xr1[d1] * yr1[d2];
                const float* gt = sG + (d1 * 9 + d2) * 28 + dz0;  // broadcast reads
                #pragma unroll
                for (int i = 0; i < 13; ++i) {
                    float g = gt[i];
                    a0[i] = fmaf(p0, g, a0[i]);
                    a1[i] = fmaf(p1, g, a1[i]);
                }
            }
        }
        if (half == 0) {
            #pragma unroll
            for (int i = 0; i < 13; ++i) {
                sZ[i * 128 + c]        = a0[i];
                sZ[(25 + i) * 128 + c] = a1[i];
            }
        } else {
            #pragma unroll
            for (int i = 0; i < 12; ++i) {              // a*[12] is the zero pad
                sZ[(13 + i) * 128 + c] = a0[i];
                sZ[(38 + i) * 128 + c] = a1[i];
            }
        }
    }
    __syncthreads();   // sZ ready; sG/sXc dead -> sOut may alias

    // Stage D: linear_out, wave -> l-aligned d-range (wz read once per block)
    if      (wave == 0) d_tile<0, 4>(sZ, wzg, sOut, lane);   // l0+l1
    else if (wave == 1) d_tile<4, 5>(sZ, wzg, sOut, lane);   // l2
    else if (wave == 2) d_tile<9, 7>(sZ, wzg, sOut, lane);   // l3
    else                d_tile<16, 9>(sZ, wzg, sOut, lane);  // l4
    __syncthreads();

    // Stage E: coalesced float4 store of both nodes' outputs
    float* po = outg + 2 * b * (CH * DZ);
    const float4* so = (const float4*)sOut;
    for (int j = tid; j < (2 * CH * DZ) / 4; j += 256)
        ((float4*)po)[j] = so[j];
}

extern "C" void kernel_launch(void* const* d_in, const int* in_sizes, int n_in,
                              void* d_out, int out_size, void* d_ws, size_t ws_size,
                              hipStream_t stream) {
    static float h_gGt[81 * 28];   // zero-init pads
    host_build_gaunt(h_gGt);
    hipMemcpyAsync(d_ws, h_gGt, sizeof(h_gGt), hipMemcpyHostToDevice, stream);

    int N = in_sizes[0] / (MULT * DIN);

    hipLaunchKernelGGL(gaunt_fused, dim3(N / 2), dim3(256), 0, stream,
                       (const float*)d_in[0], (const float*)d_in[1],
                       (const float*)d_in[2], (const float*)d_in[3],
                       (const float*)d_in[4], (float*)d_out, (const float*)d_ws);
}

// Round 13
// 111.680 us; speedup vs baseline: 1.5632x; 1.0632x over previous
//
#include <hip/hip_runtime.h>
#include <cmath>

// Static problem config (matches reference)
#define RB 20
#define RA 19
#define NPT (RB*RA)
#define DZ 25
#define DIN 9
#define MULT 128
#define CH 128

// ---------------------------------------------------------------------------
// Host: transposed dense real-Gaunt table Gt[d1*9+d2][28] in fp64 from the
// reference's own quadrature (exact bilinear identity). Cols 25..27 zero pads.
static void host_build_gaunt(float* out /* 81*28, zero-padded */) {
    const double PI = 3.14159265358979323846;
    double xq[RB], wq[RB];
    for (int i = 0; i < RB; ++i) {
        double x = cos(PI * (i + 0.75) / (RB + 0.5));
        double dp = 0.0;
        for (int it = 0; it < 100; ++it) {
            double p0 = 1.0, p1 = x;
            for (int k = 2; k <= RB; ++k) {
                double p2 = ((2.0*k - 1.0)*x*p1 - (k - 1.0)*p0) / (double)k;
                p0 = p1; p1 = p2;
            }
            dp = RB * (x*p1 - p0) / (x*x - 1.0);
            double dx = p1 / dp;
            x -= dx;
            if (fabs(dx) < 1e-15) break;
        }
        {
            double p0 = 1.0, p1 = x;
            for (int k = 2; k <= RB; ++k) {
                double p2 = ((2.0*k - 1.0)*x*p1 - (k - 1.0)*p0) / (double)k;
                p0 = p1; p1 = p2;
            }
            dp = RB * (x*p1 - p0) / (x*x - 1.0);
        }
        xq[i] = x;
        wq[i] = 2.0 / ((1.0 - x*x)*dp*dp);
    }
    static double Y[DZ][NPT];
    static double qws[NPT];
    for (int b = 0; b < RB; ++b) {
        double ct = xq[b], st = sqrt(fmax(0.0, 1.0 - ct*ct));
        double P[5][5]; double pmm = 1.0;
        for (int m = 0; m <= 4; ++m) {
            if (m > 0) pmm *= -(2.0*m - 1.0) * st;
            P[m][m] = pmm;
            if (m < 4) {
                double pp = pmm, pc = ct*(2.0*m + 1.0)*pmm;
                P[m+1][m] = pc;
                for (int l = m + 2; l <= 4; ++l) {
                    double pn = ((2.0*l - 1.0)*ct*pc - (double)(l + m - 1)*pp) / (double)(l - m);
                    P[l][m] = pn; pp = pc; pc = pn;
                }
            }
        }
        for (int a = 0; a < RA; ++a) {
            int pt = b*RA + a;
            qws[pt] = wq[b] * (2.0*PI/(double)RA);
            double alpha = 2.0*PI*(double)a/(double)RA;
            for (int l = 0; l <= 4; ++l)
                for (int m = -l; m <= l; ++m) {
                    int am = m < 0 ? -m : m;
                    double fr = 1.0;
                    for (int i = l - am + 1; i <= l + am; ++i) fr *= (double)i;
                    double nlm = sqrt((2.0*l + 1.0) / (4.0*PI) / fr);
                    double ang = (m == 0) ? 1.0
                               : (m > 0 ? sqrt(2.0)*cos(am*alpha) : sqrt(2.0)*sin(am*alpha));
                    Y[l*l + l + m][pt] = nlm * P[l][am] * ang;
                }
        }
    }
    for (int pr = 0; pr < 81; ++pr) {
        int d1 = pr / 9, d2 = pr % 9;
        for (int d = 0; d < DZ; ++d) {
            double s = 0.0;
            for (int p = 0; p < NPT; ++p)
                s += Y[d][p] * Y[d1][p] * Y[d2][p] * qws[p];
            out[pr*28 + d] = (float)s;
        }
    }
}

// ---------------------------------------------------------------------------
// Stage D helper: wave owns l-aligned d-range [D0,D0+ND) (wz_l read once per
// block); lane owns e=lane and e+64; both nodes. z read as float4 broadcasts
// (4x fewer LDS instructions than b32); l is compile-time -> w loads CSE'd.
template<int D0, int ND>
__device__ __forceinline__ void d_tile(const float* sZ, const float* __restrict__ wz,
                                       float* sOut, int lane) {
    const float s128 = 0.08838834764831845f;
    float acc[ND * 4];
    #pragma unroll
    for (int i = 0; i < ND * 4; ++i) acc[i] = 0.f;
    for (int c0 = 0; c0 < CH; c0 += 4) {
        #pragma unroll
        for (int i = 0; i < ND; ++i) {
            const int d = D0 + i;
            const int l = (d == 0) ? 0 : (d < 4) ? 1 : (d < 9) ? 2 : (d < 16) ? 3 : 4;
            float4 z0 = *(const float4*)(sZ + d * 128 + c0);          // node0 broadcast
            float4 z1 = *(const float4*)(sZ + (25 + d) * 128 + c0);   // node1 broadcast
            #pragma unroll
            for (int k = 0; k < 4; ++k) {
                float wa = wz[l * 16384 + (c0 + k) * 128 + lane];       // CSE across same-l i
                float wb = wz[l * 16384 + (c0 + k) * 128 + lane + 64];
                float zc0 = (k == 0) ? z0.x : (k == 1) ? z0.y : (k == 2) ? z0.z : z0.w;
                float zc1 = (k == 0) ? z1.x : (k == 1) ? z1.y : (k == 2) ? z1.z : z1.w;
                acc[i*4+0] = fmaf(zc0, wa, acc[i*4+0]);
                acc[i*4+1] = fmaf(zc0, wb, acc[i*4+1]);
                acc[i*4+2] = fmaf(zc1, wa, acc[i*4+2]);
                acc[i*4+3] = fmaf(zc1, wb, acc[i*4+3]);
            }
        }
    }
    #pragma unroll
    for (int i = 0; i < ND; ++i) {
        sOut[(lane) * 25 + D0 + i]            = acc[i*4+0] * s128;
        sOut[(lane + 64) * 25 + D0 + i]       = acc[i*4+1] * s128;
        sOut[(128 + lane) * 25 + D0 + i]      = acc[i*4+2] * s128;
        sOut[(128 + lane + 64) * 25 + D0 + i] = acc[i*4+3] * s128;
    }
}

// ---------------------------------------------------------------------------
// Fully fused, 2 nodes per block, z in LDS.
__global__ __launch_bounds__(256) void gaunt_fused(
    const float* __restrict__ xg, const float* __restrict__ yg,
    const float* __restrict__ wxg, const float* __restrict__ wyg,
    const float* __restrict__ wzg, float* __restrict__ outg,
    const float* __restrict__ gGt) {

    // LDS pool (floats), 15616 = 62464 B:
    //  sZ   [0,     6400)  z [n][dz][c]
    //  sXY  [6400, 11008)  x,y transposed [side][n][d*128+m]  (stages A/B)
    //  sG   [6400,  8668)  Gaunt table (stage C; aliases dead sXY)
    //  sOut [6400, 12800)  out [n][e][25]  (stage D/E)
    //  sXc  [11008,15616)  xc [side][d][n][c]  (stages B/C)
    __shared__ __align__(16) float pool[15616];
    float* sZ   = pool;
    float* sXY  = pool + 6400;
    float* sG   = pool + 6400;
    float* sOut = pool + 6400;
    float* sXc  = pool + 11008;

    const int tid  = threadIdx.x;
    const int b    = blockIdx.x;
    const int lane = tid & 63;
    const int wave = __builtin_amdgcn_readfirstlane(tid >> 6);
    const float s128 = 0.08838834764831845f;   // 1/sqrt(128)

    // Stage A: load x,y for nodes 2b,2b+1; transpose to [side][n][d*128+m]
    {
        const float4* xs = (const float4*)(xg + 2 * b * 1152);
        const float4* ys = (const float4*)(yg + 2 * b * 1152);
        for (int i = tid; i < 1152; i += 256) {
            float4 v = (i < 576) ? xs[i] : ys[i - 576];
            int r = (i < 576) ? i : i - 576;
            int base = (i < 576) ? 0 : 2304;
            int j0 = r * 4;
            #pragma unroll
            for (int k = 0; k < 4; ++k) {
                int j = j0 + k;
                int n = j / 1152;
                int jj = j - n * 1152;
                int m = jj / 9, d = jj - 9 * m;
                float val = (k == 0) ? v.x : (k == 1) ? v.y : (k == 2) ? v.z : v.w;
                sXY[base + n * 1152 + d * 128 + m] = val;
            }
        }
    }
    __syncthreads();

    // Stage B: linear_in. wave=(side,chalf), lane owns one c; both nodes.
    {
        const int side = wave >> 1, ch = wave & 1;
        const int c = ch * 64 + lane;
        const float* wb = side ? wyg : wxg;
        const float* xb = sXY + side * 2304;   // [n][d*128+m]
        float acc[18];                          // [d][n]
        #pragma unroll
        for (int i = 0; i < 18; ++i) acc[i] = 0.f;
        for (int m0 = 0; m0 < MULT; m0 += 4) {
            float w0[4], w1[4], w2[4];
            #pragma unroll
            for (int k = 0; k < 4; ++k) {
                w0[k] = wb[(m0 + k) * 128 + c];
                w1[k] = wb[16384 + (m0 + k) * 128 + c];
                w2[k] = wb[32768 + (m0 + k) * 128 + c];
            }
            #pragma unroll
            for (int d = 0; d < 9; ++d) {
                const float* wl = (d == 0) ? w0 : (d < 4) ? w1 : w2;
                float4 x0 = *(const float4*)(xb + d * 128 + m0);
                float4 x1 = *(const float4*)(xb + 1152 + d * 128 + m0);
                acc[d*2+0] = fmaf(x0.x, wl[0], acc[d*2+0]);
                acc[d*2+0] = fmaf(x0.y, wl[1], acc[d*2+0]);
                acc[d*2+0] = fmaf(x0.z, wl[2], acc[d*2+0]);
                acc[d*2+0] = fmaf(x0.w, wl[3], acc[d*2+0]);
                acc[d*2+1] = fmaf(x1.x, wl[0], acc[d*2+1]);
                acc[d*2+1] = fmaf(x1.y, wl[1], acc[d*2+1]);
                acc[d*2+1] = fmaf(x1.z, wl[2], acc[d*2+1]);
                acc[d*2+1] = fmaf(x1.w, wl[3], acc[d*2+1]);
            }
        }
        #pragma unroll
        for (int d = 0; d < 9; ++d) {
            sXc[((side * 9 + d) * 2 + 0) * 128 + c] = acc[d*2+0] * s128;
            sXc[((side * 9 + d) * 2 + 1) * 128 + c] = acc[d*2+1] * s128;
        }
    }
    __syncthreads();

    // Stage B2: Gaunt table -> LDS (over dead sXY region)
    for (int i = tid; i < 81 * 28; i += 256) sG[i] = gGt[i];
    __syncthreads();

    // Stage C: z[n][dz][c] = sum_{d1,d2} G[dz][d1,d2] xc[d1][c] yc[d2][c]
    // halves split 12/13 so both G-row offsets (0 and 12 floats = 48 B) are
    // 16B-aligned: 3x ds_read_b128 + 1x b32 per (d1,d2) instead of 13x b32.
    {
        const int c = tid & 127;
        const int half = __builtin_amdgcn_readfirstlane(tid >> 7);
        const int dz0 = half ? 12 : 0;
        float xr0[9], xr1[9], yr0[9], yr1[9];
        #pragma unroll
        for (int d = 0; d < 9; ++d) {
            xr0[d] = sXc[(d * 2 + 0) * 128 + c];
            xr1[d] = sXc[(d * 2 + 1) * 128 + c];
            yr0[d] = sXc[((9 + d) * 2 + 0) * 128 + c];
            yr1[d] = sXc[((9 + d) * 2 + 1) * 128 + c];
        }
        float a0[13], a1[13];
        #pragma unroll
        for (int i = 0; i < 13; ++i) { a0[i] = 0.f; a1[i] = 0.f; }
        for (int d1 = 0; d1 < 9; ++d1) {
            #pragma unroll
            for (int d2 = 0; d2 < 9; ++d2) {
                float p0 = xr0[d1] * yr0[d2];
                float p1 = xr1[d1] * yr1[d2];
                const float* gt = sG + (d1 * 9 + d2) * 28 + dz0;   // 16B-aligned
                float4 g0 = *(const float4*)gt;
                float4 g1 = *(const float4*)(gt + 4);
                float4 g2 = *(const float4*)(gt + 8);
                float  g3 = gt[12];            // half0: unused d12 dup; half1: dz24
                float gv[13] = {g0.x,g0.y,g0.z,g0.w, g1.x,g1.y,g1.z,g1.w,
                                g2.x,g2.y,g2.z,g2.w, g3};
                #pragma unroll
                for (int i = 0; i < 13; ++i) {
                    a0[i] = fmaf(p0, gv[i], a0[i]);
                    a1[i] = fmaf(p1, gv[i], a1[i]);
                }
            }
        }
        if (half == 0) {
            #pragma unroll
            for (int i = 0; i < 12; ++i) {      // dz 0..11 (a*[12] discarded)
                sZ[i * 128 + c]        = a0[i];
                sZ[(25 + i) * 128 + c] = a1[i];
            }
        } else {
            #pragma unroll
            for (int i = 0; i < 13; ++i) {      // dz 12..24
                sZ[(12 + i) * 128 + c] = a0[i];
                sZ[(37 + i) * 128 + c] = a1[i];
            }
        }
    }
    __syncthreads();   // sZ ready; sG/sXc dead -> sOut may alias

    // Stage D: linear_out, wave -> l-aligned d-range (wz read once per block)
    if      (wave == 0) d_tile<0, 4>(sZ, wzg, sOut, lane);   // l0+l1
    else if (wave == 1) d_tile<4, 5>(sZ, wzg, sOut, lane);   // l2
    else if (wave == 2) d_tile<9, 7>(sZ, wzg, sOut, lane);   // l3
    else                d_tile<16, 9>(sZ, wzg, sOut, lane);  // l4
    __syncthreads();

    // Stage E: coalesced float4 store of both nodes' outputs
    float* po = outg + 2 * b * (CH * DZ);
    const float4* so = (const float4*)sOut;
    for (int j = tid; j < (2 * CH * DZ) / 4; j += 256)
        ((float4*)po)[j] = so[j];
}

extern "C" void kernel_launch(void* const* d_in, const int* in_sizes, int n_in,
                              void* d_out, int out_size, void* d_ws, size_t ws_size,
                              hipStream_t stream) {
    static float h_gGt[81 * 28];   // zero-init pads
    host_build_gaunt(h_gGt);
    hipMemcpyAsync(d_ws, h_gGt, sizeof(h_gGt), hipMemcpyHostToDevice, stream);

    int N = in_sizes[0] / (MULT * DIN);

    hipLaunchKernelGGL(gaunt_fused, dim3(N / 2), dim3(256), 0, stream,
                       (const float*)d_in[0], (const float*)d_in[1],
                       (const float*)d_in[2], (const float*)d_in[3],
                       (const float*)d_in[4], (float*)d_out, (const float*)d_ws);
}